// Round 1
// baseline (280.880 us; speedup 1.0000x reference)
//
#include <hip/hip_runtime.h>
#include <hip/hip_bf16.h>
#include <stdint.h>

#define BATCH 4
#define SEQ   2048
#define NC    1024
#define NH    16
#define HD    64

typedef __bf16 bf16x8 __attribute__((ext_vector_type(8)));
typedef float  f32x4  __attribute__((ext_vector_type(4)));

#define DEV __device__ __forceinline__

DEV unsigned short f2bf(float f) {
    union { float f; unsigned u; } v; v.f = f;
    unsigned r = (v.u + 0x7fffu + ((v.u >> 16) & 1u)) >> 16;
    return (unsigned short)r;
}

// async global->LDS, 16B per lane. LDS dest must be wave-uniform base; HW adds lane*16.
#define GLDS16(gsrc, ldst)                                                           \
    __builtin_amdgcn_global_load_lds(                                                \
        (const __attribute__((address_space(1))) unsigned int*)(gsrc),               \
        (__attribute__((address_space(3))) unsigned int*)(ldst), 16, 0, 0)

// ---------------------------------------------------------------------------
// fp32 -> bf16 convert (vectorized float4 -> ushort4)
// ---------------------------------------------------------------------------
__global__ void cvt_kernel(const float* __restrict__ in, unsigned short* __restrict__ out, int n4) {
    int i = blockIdx.x * 256 + threadIdx.x;
    if (i >= n4) return;
    float4 v = reinterpret_cast<const float4*>(in)[i];
    ushort4 o;
    o.x = f2bf(v.x); o.y = f2bf(v.y); o.z = f2bf(v.z); o.w = f2bf(v.w);
    reinterpret_cast<ushort4*>(out)[i] = o;
}

// ---------------------------------------------------------------------------
// C[M,N] = A[M,K] * W[N,K]^T + bias, bf16 inputs, fp32 accum.
// 128x128 tile, BK=64, 4 waves (2x2, 64x64 each), 16x16x32 bf16 MFMA.
// global_load_lds staging with XOR chunk-swizzle (pre-swizzled global source,
// linear LDS dest) so ds_read_b128 fragment reads are bank-conflict-free.
// Epilogue: (acc + bias[n]) * (n < scale_n ? scale : 1); bf16 or fp32 out.
// ---------------------------------------------------------------------------
template <bool BF16_OUT>
__global__ __launch_bounds__(256, 2) void gemm_bt_kernel(
    const unsigned short* __restrict__ A,
    const unsigned short* __restrict__ W,
    const float* __restrict__ bias,
    void* __restrict__ Cout,
    int M, int N, int K, int scale_n, float scale)
{
    __shared__ __align__(16) char Alds[128 * 128];  // 128 rows x 64 bf16 (128B/row)
    __shared__ __align__(16) char Blds[128 * 128];

    const int tid = threadIdx.x;
    const int w = tid >> 6, l = tid & 63, g = l >> 4, lr = l & 15;
    const int nt = N >> 7;
    const int mtile = blockIdx.x / nt, ntile = blockIdx.x % nt;
    const int m0 = mtile << 7, n0 = ntile << 7;
    const int wr = (w >> 1) << 6, wc = (w & 1) << 6;

    f32x4 acc[4][4] = {};

    for (int kt = 0; kt < K; kt += 64) {
        if (kt) __syncthreads();
        // stage A tile (128x64 bf16, 16KB): 16 wave-issues of 1KB (8 rows each)
#pragma unroll
        for (int i = 0; i < 4; ++i) {
            const int issue = (i << 2) + w;
            const int row = (issue << 3) + (l >> 3);
            const int chunk = (l & 7) ^ (row & 7);
            GLDS16((const char*)(A + (size_t)(m0 + row) * K + kt) + (chunk << 4),
                   Alds + (issue << 10));
        }
#pragma unroll
        for (int i = 0; i < 4; ++i) {
            const int issue = (i << 2) + w;
            const int row = (issue << 3) + (l >> 3);
            const int chunk = (l & 7) ^ (row & 7);
            GLDS16((const char*)(W + (size_t)(n0 + row) * K + kt) + (chunk << 4),
                   Blds + (issue << 10));
        }
        __syncthreads();

#pragma unroll
        for (int kb = 0; kb < 2; ++kb) {
            bf16x8 af[4], bfr[4];
#pragma unroll
            for (int mf = 0; mf < 4; ++mf) {
                const int row = wr + (mf << 4) + lr;
                const int chunk = ((kb << 2) + g) ^ (row & 7);
                af[mf] = *reinterpret_cast<const bf16x8*>(Alds + row * 128 + (chunk << 4));
            }
#pragma unroll
            for (int nf = 0; nf < 4; ++nf) {
                const int row = wc + (nf << 4) + lr;
                const int chunk = ((kb << 2) + g) ^ (row & 7);
                bfr[nf] = *reinterpret_cast<const bf16x8*>(Blds + row * 128 + (chunk << 4));
            }
#pragma unroll
            for (int mf = 0; mf < 4; ++mf)
#pragma unroll
                for (int nf = 0; nf < 4; ++nf)
                    acc[mf][nf] = __builtin_amdgcn_mfma_f32_16x16x32_bf16(
                        af[mf], bfr[nf], acc[mf][nf], 0, 0, 0);
        }
    }

    // epilogue: C/D layout col = lane&15, row = (lane>>4)*4 + reg
#pragma unroll
    for (int mf = 0; mf < 4; ++mf) {
#pragma unroll
        for (int nf = 0; nf < 4; ++nf) {
            const int n = n0 + wc + (nf << 4) + lr;
            const float bscale = (n < scale_n) ? scale : 1.0f;
            const float bv = bias[n];
#pragma unroll
            for (int r = 0; r < 4; ++r) {
                const int m = m0 + wr + (mf << 4) + (g << 2) + r;
                float v2 = (acc[mf][nf][r] + bv) * bscale;
                if (BF16_OUT)
                    ((unsigned short*)Cout)[(size_t)m * N + n] = f2bf(v2);
                else
                    ((float*)Cout)[(size_t)m * N + n] = v2;
            }
        }
    }
}

// ---------------------------------------------------------------------------
// Causal flash attention. Block = (qb, h, b): 128 q-rows, 4 waves x 32 rows.
// qkv layout: [b, s, 3*1024] with q|k|v thirds, each [16 h][64 d].
// Computes S^T = K*Q^T (softmax row-reduce = in-lane + shfl_xor 16/32),
// online softmax, P via per-wave LDS roundtrip, O = P*V with V^T in LDS.
// Q already carries the 1/sqrt(d) scale (folded into QKV GEMM epilogue).
// ---------------------------------------------------------------------------
__global__ __launch_bounds__(256, 2) void attn_kernel(
    const unsigned short* __restrict__ qkv,  // [B*S, 3072] bf16
    unsigned short* __restrict__ ctx)        // [B*S, 1024] bf16
{
    __shared__ __align__(16) char Klds[64 * 128];   // [64 key][64 d] bf16, chunk-swizzled
    __shared__ __align__(16) char Vt[64 * 144];     // [64 d][72 key pad] bf16
    __shared__ __align__(16) char Pl[4][32 * 144];  // per-wave [32 q][72 key pad] bf16

    const int tid = threadIdx.x;
    const int w = tid >> 6, l = tid & 63, g = l >> 4, lr = l & 15;
    const int qb = blockIdx.x, h = blockIdx.y, b = blockIdx.z;

    const int q0 = (qb << 7) + (w << 5);  // wave's first q row
    const unsigned short* base = qkv + (size_t)b * SEQ * 3072 + h * 64;

    // Q fragments (B-operand: lane holds Q[q = lane&15][d = g*8+i]), scale pre-folded
    bf16x8 qfr[2][2];
#pragma unroll
    for (int qi = 0; qi < 2; ++qi)
#pragma unroll
        for (int kb = 0; kb < 2; ++kb)
            qfr[qi][kb] = *reinterpret_cast<const bf16x8*>(
                base + (size_t)(q0 + (qi << 4) + lr) * 3072 + (kb << 5) + (g << 3));

    f32x4 acc[2][4] = {};
    float mrun[2] = {-INFINITY, -INFINITY};
    float lrun[2] = {0.f, 0.f};
    char* Pw = Pl[w];

    const int ntiles = (qb + 1) << 1;
    for (int t = 0; t < ntiles; ++t) {
        const int kv0 = t << 6;
        if (t) __syncthreads();
        // stage K tile (swizzled source -> linear LDS), 8 wave-issues of 1KB
#pragma unroll
        for (int i = 0; i < 2; ++i) {
            const int issue = (i << 2) + w;
            const int row = (issue << 3) + (l >> 3);
            const int chunk = (l & 7) ^ (row & 7);
            GLDS16((const char*)(base + 1024 + (size_t)(kv0 + row) * 3072) + (chunk << 4),
                   Klds + (issue << 10));
        }
        // stage V^T (register transpose): each thread 2 x 8 bf16
#pragma unroll
        for (int i = 0; i < 2; ++i) {
            const int r = (i << 5) + (tid >> 3);
            const int c0 = (tid & 7) << 3;
            const unsigned short* vp = base + 2048 + (size_t)(kv0 + r) * 3072 + c0;
            ushort4 v0 = *reinterpret_cast<const ushort4*>(vp);
            ushort4 v1 = *reinterpret_cast<const ushort4*>(vp + 4);
            *(unsigned short*)(Vt + (c0 + 0) * 144 + r * 2) = v0.x;
            *(unsigned short*)(Vt + (c0 + 1) * 144 + r * 2) = v0.y;
            *(unsigned short*)(Vt + (c0 + 2) * 144 + r * 2) = v0.z;
            *(unsigned short*)(Vt + (c0 + 3) * 144 + r * 2) = v0.w;
            *(unsigned short*)(Vt + (c0 + 4) * 144 + r * 2) = v1.x;
            *(unsigned short*)(Vt + (c0 + 5) * 144 + r * 2) = v1.y;
            *(unsigned short*)(Vt + (c0 + 6) * 144 + r * 2) = v1.z;
            *(unsigned short*)(Vt + (c0 + 7) * 144 + r * 2) = v1.w;
        }
        __syncthreads();

        if (kv0 <= q0 + 31) {  // wave-uniform causal tile skip
            // S^T[key][q] frags: [kf 0..3][qi 0..1]
            f32x4 st[4][2] = {};
#pragma unroll
            for (int kb = 0; kb < 2; ++kb) {
                bf16x8 kfr[4];
#pragma unroll
                for (int kf = 0; kf < 4; ++kf) {
                    const int row = (kf << 4) + lr;
                    const int chunk = ((kb << 2) + g) ^ (row & 7);
                    kfr[kf] = *reinterpret_cast<const bf16x8*>(Klds + row * 128 + (chunk << 4));
                }
#pragma unroll
                for (int kf = 0; kf < 4; ++kf)
#pragma unroll
                    for (int qi = 0; qi < 2; ++qi)
                        st[kf][qi] = __builtin_amdgcn_mfma_f32_16x16x32_bf16(
                            kfr[kf], qfr[qi][kb], st[kf][qi], 0, 0, 0);
            }
            // softmax: S^T layout col(lane&15)=q, row(g*4+reg)=key
#pragma unroll
            for (int qi = 0; qi < 2; ++qi) {
                const int qg = q0 + (qi << 4) + lr;
                if (kv0 + 63 > qg) {
#pragma unroll
                    for (int kf = 0; kf < 4; ++kf)
#pragma unroll
                        for (int r = 0; r < 4; ++r) {
                            const int key = kv0 + (kf << 4) + (g << 2) + r;
                            if (key > qg) st[kf][qi][r] = -INFINITY;
                        }
                }
                float mt = -INFINITY;
#pragma unroll
                for (int kf = 0; kf < 4; ++kf)
#pragma unroll
                    for (int r = 0; r < 4; ++r) mt = fmaxf(mt, st[kf][qi][r]);
                mt = fmaxf(mt, __shfl_xor(mt, 16));
                mt = fmaxf(mt, __shfl_xor(mt, 32));
                const float mnew = fmaxf(mrun[qi], mt);
                const float corr = __expf(mrun[qi] - mnew);
                mrun[qi] = mnew;
                float rs = 0.f;
#pragma unroll
                for (int kf = 0; kf < 4; ++kf) {
                    float p0 = __expf(st[kf][qi][0] - mnew);
                    float p1 = __expf(st[kf][qi][1] - mnew);
                    float p2 = __expf(st[kf][qi][2] - mnew);
                    float p3 = __expf(st[kf][qi][3] - mnew);
                    rs += (p0 + p1) + (p2 + p3);
                    ushort4 pv;
                    pv.x = f2bf(p0); pv.y = f2bf(p1); pv.z = f2bf(p2); pv.w = f2bf(p3);
                    *reinterpret_cast<ushort4*>(
                        Pw + (qi * 16 + lr) * 144 + (((kf << 4) + (g << 2)) << 1)) = pv;
                }
                rs += __shfl_xor(rs, 16);
                rs += __shfl_xor(rs, 32);
                lrun[qi] = lrun[qi] * corr + rs;
                // rescale O accumulator rows (acc row index = g*4+r; corr lives at lane&15==row)
                float cr[4];
#pragma unroll
                for (int r = 0; r < 4; ++r) cr[r] = __shfl(corr, (l & 48) | ((g << 2) + r));
#pragma unroll
                for (int df = 0; df < 4; ++df)
#pragma unroll
                    for (int r = 0; r < 4; ++r) acc[qi][df][r] *= cr[r];
            }
            // PV: O[q][d] += P[q][key] * V[key][d]
#pragma unroll
            for (int kb = 0; kb < 2; ++kb) {
                bf16x8 pf[2], vf[4];
#pragma unroll
                for (int qi = 0; qi < 2; ++qi)
                    pf[qi] = *reinterpret_cast<const bf16x8*>(
                        Pw + (qi * 16 + lr) * 144 + (((kb << 5) + (g << 3)) << 1));
#pragma unroll
                for (int df = 0; df < 4; ++df)
                    vf[df] = *reinterpret_cast<const bf16x8*>(
                        Vt + ((df << 4) + lr) * 144 + (((kb << 5) + (g << 3)) << 1));
#pragma unroll
                for (int qi = 0; qi < 2; ++qi)
#pragma unroll
                    for (int df = 0; df < 4; ++df)
                        acc[qi][df] = __builtin_amdgcn_mfma_f32_16x16x32_bf16(
                            pf[qi], vf[df], acc[qi][df], 0, 0, 0);
            }
        }
    }

    // finalize: divide by row sum, store bf16 ctx
#pragma unroll
    for (int qi = 0; qi < 2; ++qi) {
        const float li = 1.0f / lrun[qi];
        float lr4[4];
#pragma unroll
        for (int r = 0; r < 4; ++r) lr4[r] = __shfl(li, (l & 48) | ((g << 2) + r));
#pragma unroll
        for (int df = 0; df < 4; ++df)
#pragma unroll
            for (int r = 0; r < 4; ++r) {
                const int qg = q0 + (qi << 4) + (g << 2) + r;
                const int dd = (df << 4) + lr;
                ctx[(size_t)(b * SEQ + qg) * NC + h * HD + dd] = f2bf(acc[qi][df][r] * lr4[r]);
            }
    }
}

// ---------------------------------------------------------------------------
extern "C" void kernel_launch(void* const* d_in, const int* in_sizes, int n_in,
                              void* d_out, int out_size, void* d_ws, size_t ws_size,
                              hipStream_t stream) {
    const float* x     = (const float*)d_in[0];
    const float* Wqkv  = (const float*)d_in[1];
    const float* bqkv  = (const float*)d_in[2];
    const float* Wproj = (const float*)d_in[3];
    const float* bproj = (const float*)d_in[4];
    float* out = (float*)d_out;

    const int M = BATCH * SEQ;  // 8192
    unsigned short* ws = (unsigned short*)d_ws;
    unsigned short* xb     = ws;                           // 8192*1024
    unsigned short* wqkvb  = xb + (size_t)M * NC;          // 3072*1024
    unsigned short* wprojb = wqkvb + (size_t)3 * NC * NC;  // 1024*1024
    unsigned short* qkvb   = wprojb + (size_t)NC * NC;     // 8192*3072
    unsigned short* ctxb   = qkvb + (size_t)M * 3 * NC;    // 8192*1024

    {
        int n4 = M * NC / 4;
        cvt_kernel<<<(n4 + 255) / 256, 256, 0, stream>>>(x, xb, n4);
    }
    {
        int n4 = 3 * NC * NC / 4;
        cvt_kernel<<<(n4 + 255) / 256, 256, 0, stream>>>(Wqkv, wqkvb, n4);
    }
    {
        int n4 = NC * NC / 4;
        cvt_kernel<<<(n4 + 255) / 256, 256, 0, stream>>>(Wproj, wprojb, n4);
    }

    // qkv = x @ Wqkv^T + b; q-third scaled by 1/sqrt(64) (folds attention scale)
    gemm_bt_kernel<true><<<(M / 128) * (3 * NC / 128), 256, 0, stream>>>(
        xb, wqkvb, bqkv, qkvb, M, 3 * NC, NC, NC, 0.125f);

    attn_kernel<<<dim3(SEQ / 128, NH, BATCH), 256, 0, stream>>>(qkvb, ctxb);

    // out = ctx @ Wproj^T + b (fp32 out)
    gemm_bt_kernel<false><<<(M / 128) * (NC / 128), 256, 0, stream>>>(
        ctxb, wprojb, bproj, out, M, NC, NC, 0, 1.0f);
}

// Round 2
// 184.080 us; speedup vs baseline: 1.5259x; 1.5259x over previous
//
#include <hip/hip_runtime.h>
#include <hip/hip_bf16.h>
#include <stdint.h>

#define BATCH 4
#define SEQ   2048
#define NC    1024
#define NH    16
#define HD    64
#define NT    16   // q-tiles of 128 rows

typedef __bf16 bf16x8 __attribute__((ext_vector_type(8)));
typedef __bf16 bf16x4 __attribute__((ext_vector_type(4)));
typedef float  f32x4  __attribute__((ext_vector_type(4)));

#define DEV __device__ __forceinline__

DEV unsigned short f2bf(float f) {
    union { float f; unsigned u; } v; v.f = f;
    unsigned r = (v.u + 0x7fffu + ((v.u >> 16) & 1u)) >> 16;
    return (unsigned short)r;
}

DEV float fast_exp2(float x) {
#if __has_builtin(__builtin_amdgcn_exp2f)
    return __builtin_amdgcn_exp2f(x);
#else
    return exp2f(x);
#endif
}

// async global->LDS, 16B per lane. LDS dest must be wave-uniform base; HW adds lane*16.
#define GLDS16(gsrc, ldst)                                                           \
    __builtin_amdgcn_global_load_lds(                                                \
        (const __attribute__((address_space(1))) unsigned int*)(gsrc),               \
        (__attribute__((address_space(3))) unsigned int*)(ldst), 16, 0, 0)

// ---------------------------------------------------------------------------
// fp32 -> bf16 convert (vectorized float4 -> ushort4)
// ---------------------------------------------------------------------------
__global__ void cvt_kernel(const float* __restrict__ in, unsigned short* __restrict__ out, int n4) {
    int i = blockIdx.x * 256 + threadIdx.x;
    if (i >= n4) return;
    float4 v = reinterpret_cast<const float4*>(in)[i];
    ushort4 o;
    o.x = f2bf(v.x); o.y = f2bf(v.y); o.z = f2bf(v.z); o.w = f2bf(v.w);
    reinterpret_cast<ushort4*>(out)[i] = o;
}

// ---------------------------------------------------------------------------
// C[M,N] = A[M,K] * W[N,K]^T + bias, bf16 inputs, fp32 accum. (unchanged)
// ---------------------------------------------------------------------------
template <bool BF16_OUT>
__global__ __launch_bounds__(256, 2) void gemm_bt_kernel(
    const unsigned short* __restrict__ A,
    const unsigned short* __restrict__ W,
    const float* __restrict__ bias,
    void* __restrict__ Cout,
    int M, int N, int K, int scale_n, float scale)
{
    __shared__ __align__(16) char Alds[128 * 128];
    __shared__ __align__(16) char Blds[128 * 128];

    const int tid = threadIdx.x;
    const int w = tid >> 6, l = tid & 63, g = l >> 4, lr = l & 15;
    const int nt = N >> 7;
    const int mtile = blockIdx.x / nt, ntile = blockIdx.x % nt;
    const int m0 = mtile << 7, n0 = ntile << 7;
    const int wr = (w >> 1) << 6, wc = (w & 1) << 6;

    f32x4 acc[4][4] = {};

    for (int kt = 0; kt < K; kt += 64) {
        if (kt) __syncthreads();
#pragma unroll
        for (int i = 0; i < 4; ++i) {
            const int issue = (i << 2) + w;
            const int row = (issue << 3) + (l >> 3);
            const int chunk = (l & 7) ^ (row & 7);
            GLDS16((const char*)(A + (size_t)(m0 + row) * K + kt) + (chunk << 4),
                   Alds + (issue << 10));
        }
#pragma unroll
        for (int i = 0; i < 4; ++i) {
            const int issue = (i << 2) + w;
            const int row = (issue << 3) + (l >> 3);
            const int chunk = (l & 7) ^ (row & 7);
            GLDS16((const char*)(W + (size_t)(n0 + row) * K + kt) + (chunk << 4),
                   Blds + (issue << 10));
        }
        __syncthreads();

#pragma unroll
        for (int kb = 0; kb < 2; ++kb) {
            bf16x8 af[4], bfr[4];
#pragma unroll
            for (int mf = 0; mf < 4; ++mf) {
                const int row = wr + (mf << 4) + lr;
                const int chunk = ((kb << 2) + g) ^ (row & 7);
                af[mf] = *reinterpret_cast<const bf16x8*>(Alds + row * 128 + (chunk << 4));
            }
#pragma unroll
            for (int nf = 0; nf < 4; ++nf) {
                const int row = wc + (nf << 4) + lr;
                const int chunk = ((kb << 2) + g) ^ (row & 7);
                bfr[nf] = *reinterpret_cast<const bf16x8*>(Blds + row * 128 + (chunk << 4));
            }
#pragma unroll
            for (int mf = 0; mf < 4; ++mf)
#pragma unroll
                for (int nf = 0; nf < 4; ++nf)
                    acc[mf][nf] = __builtin_amdgcn_mfma_f32_16x16x32_bf16(
                        af[mf], bfr[nf], acc[mf][nf], 0, 0, 0);
        }
    }

#pragma unroll
    for (int mf = 0; mf < 4; ++mf) {
#pragma unroll
        for (int nf = 0; nf < 4; ++nf) {
            const int n = n0 + wc + (nf << 4) + lr;
            const float bscale = (n < scale_n) ? scale : 1.0f;
            const float bv = bias[n];
#pragma unroll
            for (int r = 0; r < 4; ++r) {
                const int m = m0 + wr + (mf << 4) + (g << 2) + r;
                float v2 = (acc[mf][nf][r] + bv) * bscale;
                if (BF16_OUT)
                    ((unsigned short*)Cout)[(size_t)m * N + n] = f2bf(v2);
                else
                    ((float*)Cout)[(size_t)m * N + n] = v2;
            }
        }
    }
}

// ---------------------------------------------------------------------------
// Causal flash attention, load-balanced + double-buffered.
// Block = (pair p, h, b): processes q-tiles p and 15-p (uniform 34 KV-tiles).
// 4 waves x 32 q-rows. K double-buffered via global_load_lds (chunk-swizzled
// source, linear LDS); V double-buffered via reg-staged transpose:
// 8x b32 global loads issued BEFORE compute, 2x ds_write_b128 AFTER (T14).
// V^T rows padded to 144B -> all b128 LDS traffic at the bank floor.
// Softmax in exp2 domain (log2e folded into q scale upstream).
// ---------------------------------------------------------------------------
__global__ __launch_bounds__(256, 2) void attn_kernel(
    const unsigned short* __restrict__ qkv,  // [B*S, 3072] bf16
    unsigned short* __restrict__ ctx)        // [B*S, 1024] bf16
{
    __shared__ __align__(16) char Klds[2][8192];      // [64 key][64 d], chunk-swizzled
    __shared__ __align__(16) char Vt[2][64 * 144];    // [64 d][72 key pad] bf16
    __shared__ __align__(16) char Pl[4][32 * 144];    // per-wave [32 q][72 key pad] bf16

    const int tid = threadIdx.x;
    const int w = tid >> 6, l = tid & 63, g = l >> 4, lr = l & 15;
    const int p = blockIdx.x, h = blockIdx.y, b = blockIdx.z;
    const unsigned short* base = qkv + (size_t)b * SEQ * 3072 + h * 64;
    char* Pw = Pl[w];

    // V staging coords: thread loads 8 keys x 2 d (b32 each), writes 2 b128 rows
    const int vkey0 = (tid >> 5) << 3;  // 0..56 step 8
    const int vd0   = (tid & 31) << 1;  // 0..62 step 2
    const unsigned short* vbase = base + 2048 + (size_t)vkey0 * 3072 + vd0;

    for (int pass = 0; pass < 2; ++pass) {
        const int qt = pass ? (NT - 1 - p) : p;
        const int q0 = (qt << 7) + (w << 5);
        const int ntiles = (qt + 1) << 1;

        bf16x8 qfr[2][2];
#pragma unroll
        for (int qi = 0; qi < 2; ++qi)
#pragma unroll
            for (int kb = 0; kb < 2; ++kb)
                qfr[qi][kb] = *reinterpret_cast<const bf16x8*>(
                    base + (size_t)(q0 + (qi << 4) + lr) * 3072 + (kb << 5) + (g << 3));

        f32x4 acc[2][4] = {};
        float mrun[2] = {-INFINITY, -INFINITY};
        float lrun[2] = {0.f, 0.f};

        uint32_t vreg[8];

        // ---- prologue: stage tile 0 ----
#pragma unroll
        for (int i = 0; i < 8; ++i)
            vreg[i] = *reinterpret_cast<const uint32_t*>(vbase + (size_t)i * 3072);
#pragma unroll
        for (int i = 0; i < 2; ++i) {
            const int issue = (i << 2) + w;
            const int row = (issue << 3) + (l >> 3);
            const int chunk = (l & 7) ^ (row & 7);
            GLDS16((const char*)(base + 1024 + (size_t)row * 3072) + (chunk << 4),
                   Klds[0] + (issue << 10));
        }
        {
            uint4 a, bq;
            a.x = (vreg[0] & 0xffffu) | (vreg[1] << 16);
            a.y = (vreg[2] & 0xffffu) | (vreg[3] << 16);
            a.z = (vreg[4] & 0xffffu) | (vreg[5] << 16);
            a.w = (vreg[6] & 0xffffu) | (vreg[7] << 16);
            bq.x = (vreg[0] >> 16) | (vreg[1] & 0xffff0000u);
            bq.y = (vreg[2] >> 16) | (vreg[3] & 0xffff0000u);
            bq.z = (vreg[4] >> 16) | (vreg[5] & 0xffff0000u);
            bq.w = (vreg[6] >> 16) | (vreg[7] & 0xffff0000u);
            *reinterpret_cast<uint4*>(Vt[0] + vd0 * 144 + vkey0 * 2) = a;
            *reinterpret_cast<uint4*>(Vt[0] + (vd0 + 1) * 144 + vkey0 * 2) = bq;
        }
        __syncthreads();

        for (int t = 0; t < ntiles; ++t) {
            const int cur = t & 1;
            const int kv0 = t << 6;
            const bool pf_ = (t + 1 < ntiles);

            if (pf_) {
                const int kv1 = kv0 + 64;
                // issue V loads (consumed after compute) then K gload_lds
#pragma unroll
                for (int i = 0; i < 8; ++i)
                    vreg[i] = *reinterpret_cast<const uint32_t*>(
                        vbase + (size_t)(kv1 + i) * 3072);
#pragma unroll
                for (int i = 0; i < 2; ++i) {
                    const int issue = (i << 2) + w;
                    const int row = (issue << 3) + (l >> 3);
                    const int chunk = (l & 7) ^ (row & 7);
                    GLDS16((const char*)(base + 1024 + (size_t)(kv1 + row) * 3072) + (chunk << 4),
                           Klds[cur ^ 1] + (issue << 10));
                }
            }

            if (kv0 <= q0 + 31) {  // wave-uniform causal tile skip
                // ---- QK^T (S^T = K * Q^T) ----
                f32x4 st[4][2] = {};
#pragma unroll
                for (int kb = 0; kb < 2; ++kb) {
                    bf16x8 kfr[4];
#pragma unroll
                    for (int kf = 0; kf < 4; ++kf) {
                        const int row = (kf << 4) + lr;
                        const int chunk = ((kb << 2) + g) ^ (row & 7);
                        kfr[kf] = *reinterpret_cast<const bf16x8*>(
                            Klds[cur] + row * 128 + (chunk << 4));
                    }
#pragma unroll
                    for (int kf = 0; kf < 4; ++kf)
#pragma unroll
                        for (int qi = 0; qi < 2; ++qi)
                            st[kf][qi] = __builtin_amdgcn_mfma_f32_16x16x32_bf16(
                                kfr[kf], qfr[qi][kb], st[kf][qi], 0, 0, 0);
                }
                // ---- online softmax (exp2 domain) ----
#pragma unroll
                for (int qi = 0; qi < 2; ++qi) {
                    const int qg = q0 + (qi << 4) + lr;
                    if (kv0 + 63 > qg) {
#pragma unroll
                        for (int kf = 0; kf < 4; ++kf)
#pragma unroll
                            for (int r = 0; r < 4; ++r) {
                                const int key = kv0 + (kf << 4) + (g << 2) + r;
                                if (key > qg) st[kf][qi][r] = -INFINITY;
                            }
                    }
                    float mt = -INFINITY;
#pragma unroll
                    for (int kf = 0; kf < 4; ++kf)
#pragma unroll
                        for (int r = 0; r < 4; ++r) mt = fmaxf(mt, st[kf][qi][r]);
                    mt = fmaxf(mt, __shfl_xor(mt, 16));
                    mt = fmaxf(mt, __shfl_xor(mt, 32));
                    const float mnew = fmaxf(mrun[qi], mt);
                    const float corr = fast_exp2(mrun[qi] - mnew);
                    mrun[qi] = mnew;
                    float rs = 0.f;
#pragma unroll
                    for (int kf = 0; kf < 4; ++kf) {
                        float p0 = fast_exp2(st[kf][qi][0] - mnew);
                        float p1 = fast_exp2(st[kf][qi][1] - mnew);
                        float p2 = fast_exp2(st[kf][qi][2] - mnew);
                        float p3 = fast_exp2(st[kf][qi][3] - mnew);
                        rs += (p0 + p1) + (p2 + p3);
                        bf16x4 pv = {(__bf16)p0, (__bf16)p1, (__bf16)p2, (__bf16)p3};
                        *reinterpret_cast<bf16x4*>(
                            Pw + (qi * 16 + lr) * 144 + (((kf << 4) + (g << 2)) << 1)) = pv;
                    }
                    rs += __shfl_xor(rs, 16);
                    rs += __shfl_xor(rs, 32);
                    lrun[qi] = lrun[qi] * corr + rs;
                    float cr[4];
#pragma unroll
                    for (int r = 0; r < 4; ++r) cr[r] = __shfl(corr, (l & 48) | ((g << 2) + r));
#pragma unroll
                    for (int df = 0; df < 4; ++df)
#pragma unroll
                        for (int r = 0; r < 4; ++r) acc[qi][df][r] *= cr[r];
                }
                // ---- PV: O[q][d] += P[q][key] * V[key][d] ----
#pragma unroll
                for (int kb = 0; kb < 2; ++kb) {
                    bf16x8 pfv[2], vf[4];
#pragma unroll
                    for (int qi = 0; qi < 2; ++qi)
                        pfv[qi] = *reinterpret_cast<const bf16x8*>(
                            Pw + (qi * 16 + lr) * 144 + (((kb << 5) + (g << 3)) << 1));
#pragma unroll
                    for (int df = 0; df < 4; ++df)
                        vf[df] = *reinterpret_cast<const bf16x8*>(
                            Vt[cur] + ((df << 4) + lr) * 144 + (((kb << 5) + (g << 3)) << 1));
#pragma unroll
                    for (int qi = 0; qi < 2; ++qi)
#pragma unroll
                        for (int df = 0; df < 4; ++df)
                            acc[qi][df] = __builtin_amdgcn_mfma_f32_16x16x32_bf16(
                                pfv[qi], vf[df], acc[qi][df], 0, 0, 0);
                }
            }

            if (pf_) {
                // write V^T for t+1 (vmcnt wait inserted by compiler), then barrier
                uint4 a, bq;
                a.x = (vreg[0] & 0xffffu) | (vreg[1] << 16);
                a.y = (vreg[2] & 0xffffu) | (vreg[3] << 16);
                a.z = (vreg[4] & 0xffffu) | (vreg[5] << 16);
                a.w = (vreg[6] & 0xffffu) | (vreg[7] << 16);
                bq.x = (vreg[0] >> 16) | (vreg[1] & 0xffff0000u);
                bq.y = (vreg[2] >> 16) | (vreg[3] & 0xffff0000u);
                bq.z = (vreg[4] >> 16) | (vreg[5] & 0xffff0000u);
                bq.w = (vreg[6] >> 16) | (vreg[7] & 0xffff0000u);
                char* vt = Vt[cur ^ 1];
                *reinterpret_cast<uint4*>(vt + vd0 * 144 + vkey0 * 2) = a;
                *reinterpret_cast<uint4*>(vt + (vd0 + 1) * 144 + vkey0 * 2) = bq;
                __syncthreads();
            }
        }

        // ---- finalize: divide by row sum, store bf16 ctx ----
#pragma unroll
        for (int qi = 0; qi < 2; ++qi) {
            const float li = 1.0f / lrun[qi];
            float lr4[4];
#pragma unroll
            for (int r = 0; r < 4; ++r) lr4[r] = __shfl(li, (l & 48) | ((g << 2) + r));
#pragma unroll
            for (int df = 0; df < 4; ++df)
#pragma unroll
                for (int r = 0; r < 4; ++r) {
                    const int qg = q0 + (qi << 4) + (g << 2) + r;
                    const int dd = (df << 4) + lr;
                    ctx[(size_t)(b * SEQ + qg) * NC + h * HD + dd] =
                        f2bf(acc[qi][df][r] * lr4[r]);
                }
        }
    }
}

// ---------------------------------------------------------------------------
extern "C" void kernel_launch(void* const* d_in, const int* in_sizes, int n_in,
                              void* d_out, int out_size, void* d_ws, size_t ws_size,
                              hipStream_t stream) {
    const float* x     = (const float*)d_in[0];
    const float* Wqkv  = (const float*)d_in[1];
    const float* bqkv  = (const float*)d_in[2];
    const float* Wproj = (const float*)d_in[3];
    const float* bproj = (const float*)d_in[4];
    float* out = (float*)d_out;

    const int M = BATCH * SEQ;  // 8192
    unsigned short* ws = (unsigned short*)d_ws;
    unsigned short* xb     = ws;                           // 8192*1024
    unsigned short* wqkvb  = xb + (size_t)M * NC;          // 3072*1024
    unsigned short* wprojb = wqkvb + (size_t)3 * NC * NC;  // 1024*1024
    unsigned short* qkvb   = wprojb + (size_t)NC * NC;     // 8192*3072
    unsigned short* ctxb   = qkvb + (size_t)M * 3 * NC;    // 8192*1024

    {
        int n4 = M * NC / 4;
        cvt_kernel<<<(n4 + 255) / 256, 256, 0, stream>>>(x, xb, n4);
    }
    {
        int n4 = 3 * NC * NC / 4;
        cvt_kernel<<<(n4 + 255) / 256, 256, 0, stream>>>(Wqkv, wqkvb, n4);
    }
    {
        int n4 = NC * NC / 4;
        cvt_kernel<<<(n4 + 255) / 256, 256, 0, stream>>>(Wproj, wprojb, n4);
    }

    // qkv = x @ Wqkv^T + b; q-third scaled by (1/sqrt(64))*log2(e) -> exp2 softmax
    gemm_bt_kernel<true><<<(M / 128) * (3 * NC / 128), 256, 0, stream>>>(
        xb, wqkvb, bqkv, qkvb, M, 3 * NC, NC, NC, 0.18033688011112042f);

    attn_kernel<<<dim3(SEQ / 256, NH, BATCH), 256, 0, stream>>>(qkvb, ctxb);

    // out = ctx @ Wproj^T + b (fp32 out)
    gemm_bt_kernel<false><<<(M / 128) * (NC / 128), 256, 0, stream>>>(
        ctxb, wprojb, bproj, out, M, NC, NC, 0, 1.0f);
}

// Round 3
// 173.263 us; speedup vs baseline: 1.6211x; 1.0624x over previous
//
#include <hip/hip_runtime.h>
#include <hip/hip_bf16.h>
#include <stdint.h>

#define BATCH 4
#define SEQ   2048
#define NC    1024
#define NH    16
#define HD    64
#define NT    16   // q-tiles of 128 rows

typedef __bf16 bf16x8 __attribute__((ext_vector_type(8)));
typedef __bf16 bf16x4 __attribute__((ext_vector_type(4)));
typedef float  f32x4  __attribute__((ext_vector_type(4)));

#define DEV __device__ __forceinline__

DEV unsigned short f2bf(float f) {
    union { float f; unsigned u; } v; v.f = f;
    unsigned r = (v.u + 0x7fffu + ((v.u >> 16) & 1u)) >> 16;
    return (unsigned short)r;
}

DEV float fast_exp2(float x) {
#if __has_builtin(__builtin_amdgcn_exp2f)
    return __builtin_amdgcn_exp2f(x);
#else
    return exp2f(x);
#endif
}

// async global->LDS, 16B per lane. LDS dest must be wave-uniform base; HW adds lane*16.
#define GLDS16(gsrc, ldst)                                                           \
    __builtin_amdgcn_global_load_lds(                                                \
        (const __attribute__((address_space(1))) unsigned int*)(gsrc),               \
        (__attribute__((address_space(3))) unsigned int*)(ldst), 16, 0, 0)

// ---------------------------------------------------------------------------
// fp32 -> bf16 convert (vectorized float4 -> ushort4)
// ---------------------------------------------------------------------------
__global__ void cvt_kernel(const float* __restrict__ in, unsigned short* __restrict__ out, int n4) {
    int i = blockIdx.x * 256 + threadIdx.x;
    if (i >= n4) return;
    float4 v = reinterpret_cast<const float4*>(in)[i];
    ushort4 o;
    o.x = f2bf(v.x); o.y = f2bf(v.y); o.z = f2bf(v.z); o.w = f2bf(v.w);
    reinterpret_cast<ushort4*>(out)[i] = o;
}

// ---------------------------------------------------------------------------
// C[M,N] = A[M,K] * W[N,K]^T + bias, bf16 inputs, fp32 accum.
// 128x128 tile, BK=64, 4 waves (2x2), 16x16x32 bf16 MFMA, gload_lds staging
// with XOR chunk-swizzle. XCD-aware block swizzle (grid % 8 == 0 for all
// launches here) so each XCD's L2 serves a contiguous mtile strip.
// ---------------------------------------------------------------------------
template <bool BF16_OUT>
__global__ __launch_bounds__(256, 2) void gemm_bt_kernel(
    const unsigned short* __restrict__ A,
    const unsigned short* __restrict__ W,
    const float* __restrict__ bias,
    void* __restrict__ Cout,
    int M, int N, int K, int scale_n, float scale)
{
    __shared__ __align__(16) char Alds[128 * 128];
    __shared__ __align__(16) char Blds[128 * 128];

    const int tid = threadIdx.x;
    const int w = tid >> 6, l = tid & 63, g = l >> 4, lr = l & 15;
    const int nt = N >> 7;
    const int cpx = gridDim.x >> 3;
    const int bid = (blockIdx.x & 7) * cpx + (blockIdx.x >> 3);
    const int mtile = bid / nt, ntile = bid % nt;
    const int m0 = mtile << 7, n0 = ntile << 7;
    const int wr = (w >> 1) << 6, wc = (w & 1) << 6;

    f32x4 acc[4][4] = {};

    for (int kt = 0; kt < K; kt += 64) {
        if (kt) __syncthreads();
#pragma unroll
        for (int i = 0; i < 4; ++i) {
            const int issue = (i << 2) + w;
            const int row = (issue << 3) + (l >> 3);
            const int chunk = (l & 7) ^ (row & 7);
            GLDS16((const char*)(A + (size_t)(m0 + row) * K + kt) + (chunk << 4),
                   Alds + (issue << 10));
        }
#pragma unroll
        for (int i = 0; i < 4; ++i) {
            const int issue = (i << 2) + w;
            const int row = (issue << 3) + (l >> 3);
            const int chunk = (l & 7) ^ (row & 7);
            GLDS16((const char*)(W + (size_t)(n0 + row) * K + kt) + (chunk << 4),
                   Blds + (issue << 10));
        }
        __syncthreads();

#pragma unroll
        for (int kb = 0; kb < 2; ++kb) {
            bf16x8 af[4], bfr[4];
#pragma unroll
            for (int mf = 0; mf < 4; ++mf) {
                const int row = wr + (mf << 4) + lr;
                const int chunk = ((kb << 2) + g) ^ (row & 7);
                af[mf] = *reinterpret_cast<const bf16x8*>(Alds + row * 128 + (chunk << 4));
            }
#pragma unroll
            for (int nf = 0; nf < 4; ++nf) {
                const int row = wc + (nf << 4) + lr;
                const int chunk = ((kb << 2) + g) ^ (row & 7);
                bfr[nf] = *reinterpret_cast<const bf16x8*>(Blds + row * 128 + (chunk << 4));
            }
#pragma unroll
            for (int mf = 0; mf < 4; ++mf)
#pragma unroll
                for (int nf = 0; nf < 4; ++nf)
                    acc[mf][nf] = __builtin_amdgcn_mfma_f32_16x16x32_bf16(
                        af[mf], bfr[nf], acc[mf][nf], 0, 0, 0);
        }
    }

#pragma unroll
    for (int mf = 0; mf < 4; ++mf) {
#pragma unroll
        for (int nf = 0; nf < 4; ++nf) {
            const int n = n0 + wc + (nf << 4) + lr;
            const float bscale = (n < scale_n) ? scale : 1.0f;
            const float bv = bias[n];
#pragma unroll
            for (int r = 0; r < 4; ++r) {
                const int m = m0 + wr + (mf << 4) + (g << 2) + r;
                float v2 = (acc[mf][nf][r] + bv) * bscale;
                if (BF16_OUT)
                    ((unsigned short*)Cout)[(size_t)m * N + n] = f2bf(v2);
                else
                    ((float*)Cout)[(size_t)m * N + n] = v2;
            }
        }
    }
}

// ---------------------------------------------------------------------------
// Causal flash attention, load-balanced + double-buffered, O^T accumulator.
// 1D grid, XCD-swizzled so the 8 q-pair blocks of one (h,b) share an XCD L2.
// Block = (pair p, h, b): q-tiles p and 15-p (uniform 34 KV-tiles), 4 waves
// x 32 q-rows. K dbuf via gload_lds (chunk-swizzled source); V dbuf via
// reg-staged transpose (T14: loads early, ds_write after compute).
// S^T = K*Q^T puts q on lane&15; PV computes O^T = V^T * P^T so corr/lrun/
// finalize are per-lane (no cross-lane broadcasts). Defer-max (THR=8 in
// exp2 domain) skips rescale on max-stable tiles.
// ---------------------------------------------------------------------------
__global__ __launch_bounds__(256, 2) void attn_kernel(
    const unsigned short* __restrict__ qkv,  // [B*S, 3072] bf16
    unsigned short* __restrict__ ctx)        // [B*S, 1024] bf16
{
    __shared__ __align__(16) char Klds[2][8192];      // [64 key][64 d], chunk-swizzled
    __shared__ __align__(16) char Vt[2][64 * 144];    // [64 d][72 key pad] bf16
    __shared__ __align__(16) char Pl[4][32 * 144];    // per-wave [32 q][72 key pad] bf16

    const int tid = threadIdx.x;
    const int w = tid >> 6, l = tid & 63, g = l >> 4, lr = l & 15;
    const int cpx = gridDim.x >> 3;  // 64
    const int bid = (blockIdx.x & 7) * cpx + (blockIdx.x >> 3);
    const int p = bid & 7, h = (bid >> 3) & 15, b = bid >> 7;
    const unsigned short* base = qkv + (size_t)b * SEQ * 3072 + h * 64;
    char* Pw = Pl[w];

    // V staging coords: thread loads 8 keys x 2 d (b32 each), writes 2 b128 rows
    const int vkey0 = (tid >> 5) << 3;  // 0..56 step 8
    const int vd0   = (tid & 31) << 1;  // 0..62 step 2
    const unsigned short* vbase = base + 2048 + (size_t)vkey0 * 3072 + vd0;

    for (int pass = 0; pass < 2; ++pass) {
        const int qt = pass ? (NT - 1 - p) : p;
        const int q0 = (qt << 7) + (w << 5);
        const int ntiles = (qt + 1) << 1;  // always even (buffer-parity invariant)

        bf16x8 qfr[2][2];
#pragma unroll
        for (int qi = 0; qi < 2; ++qi)
#pragma unroll
            for (int kb = 0; kb < 2; ++kb)
                qfr[qi][kb] = *reinterpret_cast<const bf16x8*>(
                    base + (size_t)(q0 + (qi << 4) + lr) * 3072 + (kb << 5) + (g << 3));

        f32x4 acc[2][4] = {};  // acc[qi][df] = O^T: row(g*4+r)=d, col(lane&15)=q
        float mrun[2] = {-INFINITY, -INFINITY};
        float lrun[2] = {0.f, 0.f};

        uint32_t vreg[8];

        // ---- prologue: stage tile 0 ----
#pragma unroll
        for (int i = 0; i < 8; ++i)
            vreg[i] = *reinterpret_cast<const uint32_t*>(vbase + (size_t)i * 3072);
#pragma unroll
        for (int i = 0; i < 2; ++i) {
            const int issue = (i << 2) + w;
            const int row = (issue << 3) + (l >> 3);
            const int chunk = (l & 7) ^ (row & 7);
            GLDS16((const char*)(base + 1024 + (size_t)row * 3072) + (chunk << 4),
                   Klds[0] + (issue << 10));
        }
        {
            uint4 a, bq;
            a.x = (vreg[0] & 0xffffu) | (vreg[1] << 16);
            a.y = (vreg[2] & 0xffffu) | (vreg[3] << 16);
            a.z = (vreg[4] & 0xffffu) | (vreg[5] << 16);
            a.w = (vreg[6] & 0xffffu) | (vreg[7] << 16);
            bq.x = (vreg[0] >> 16) | (vreg[1] & 0xffff0000u);
            bq.y = (vreg[2] >> 16) | (vreg[3] & 0xffff0000u);
            bq.z = (vreg[4] >> 16) | (vreg[5] & 0xffff0000u);
            bq.w = (vreg[6] >> 16) | (vreg[7] & 0xffff0000u);
            *reinterpret_cast<uint4*>(Vt[0] + vd0 * 144 + vkey0 * 2) = a;
            *reinterpret_cast<uint4*>(Vt[0] + (vd0 + 1) * 144 + vkey0 * 2) = bq;
        }
        __syncthreads();

        for (int t = 0; t < ntiles; ++t) {
            const int cur = t & 1;
            const int kv0 = t << 6;
            const bool pf_ = (t + 1 < ntiles);

            if (pf_) {
                const int kv1 = kv0 + 64;
#pragma unroll
                for (int i = 0; i < 8; ++i)
                    vreg[i] = *reinterpret_cast<const uint32_t*>(
                        vbase + (size_t)(kv1 + i) * 3072);
#pragma unroll
                for (int i = 0; i < 2; ++i) {
                    const int issue = (i << 2) + w;
                    const int row = (issue << 3) + (l >> 3);
                    const int chunk = (l & 7) ^ (row & 7);
                    GLDS16((const char*)(base + 1024 + (size_t)(kv1 + row) * 3072) + (chunk << 4),
                           Klds[cur ^ 1] + (issue << 10));
                }
            }

            if (kv0 <= q0 + 31) {  // wave-uniform causal tile skip
                // ---- QK^T (S^T = K * Q^T): col=q, row=key ----
                f32x4 st[4][2] = {};
#pragma unroll
                for (int kb = 0; kb < 2; ++kb) {
                    bf16x8 kfr[4];
#pragma unroll
                    for (int kf = 0; kf < 4; ++kf) {
                        const int row = (kf << 4) + lr;
                        const int chunk = ((kb << 2) + g) ^ (row & 7);
                        kfr[kf] = *reinterpret_cast<const bf16x8*>(
                            Klds[cur] + row * 128 + (chunk << 4));
                    }
#pragma unroll
                    for (int kf = 0; kf < 4; ++kf)
#pragma unroll
                        for (int qi = 0; qi < 2; ++qi)
                            st[kf][qi] = __builtin_amdgcn_mfma_f32_16x16x32_bf16(
                                kfr[kf], qfr[qi][kb], st[kf][qi], 0, 0, 0);
                }
                // ---- online softmax (exp2 domain), per-lane corr ----
#pragma unroll
                for (int qi = 0; qi < 2; ++qi) {
                    if (kv0 + 63 > q0 + (qi << 4)) {  // diagonal tile: mask (uniform branch)
                        const int qg = q0 + (qi << 4) + lr;
#pragma unroll
                        for (int kf = 0; kf < 4; ++kf)
#pragma unroll
                            for (int r = 0; r < 4; ++r) {
                                const int key = kv0 + (kf << 4) + (g << 2) + r;
                                if (key > qg) st[kf][qi][r] = -INFINITY;
                            }
                    }
                    float mt = -INFINITY;
#pragma unroll
                    for (int kf = 0; kf < 4; ++kf)
#pragma unroll
                        for (int r = 0; r < 4; ++r) mt = fmaxf(mt, st[kf][qi][r]);
                    mt = fmaxf(mt, __shfl_xor(mt, 16));
                    mt = fmaxf(mt, __shfl_xor(mt, 32));
                    if (__any(mt > mrun[qi] + 8.0f)) {  // defer-max: rescale only on growth
                        const float mnew = fmaxf(mrun[qi], mt);
                        const float corr = fast_exp2(mrun[qi] - mnew);
                        mrun[qi] = mnew;
                        lrun[qi] *= corr;
#pragma unroll
                        for (int df = 0; df < 4; ++df)
#pragma unroll
                            for (int r = 0; r < 4; ++r) acc[qi][df][r] *= corr;
                    }
                    float rs = 0.f;
#pragma unroll
                    for (int kf = 0; kf < 4; ++kf) {
                        float p0 = fast_exp2(st[kf][qi][0] - mrun[qi]);
                        float p1 = fast_exp2(st[kf][qi][1] - mrun[qi]);
                        float p2 = fast_exp2(st[kf][qi][2] - mrun[qi]);
                        float p3 = fast_exp2(st[kf][qi][3] - mrun[qi]);
                        rs += (p0 + p1) + (p2 + p3);
                        bf16x4 pv = {(__bf16)p0, (__bf16)p1, (__bf16)p2, (__bf16)p3};
                        *reinterpret_cast<bf16x4*>(
                            Pw + (qi * 16 + lr) * 144 + (((kf << 4) + (g << 2)) << 1)) = pv;
                    }
                    rs += __shfl_xor(rs, 16);
                    rs += __shfl_xor(rs, 32);
                    lrun[qi] += rs;
                }
                // ---- PV as O^T: acc[qi][df] = V-frag(A) x P-frag(B) ----
#pragma unroll
                for (int kb = 0; kb < 2; ++kb) {
                    bf16x8 pfv[2], vf[4];
#pragma unroll
                    for (int qi = 0; qi < 2; ++qi)
                        pfv[qi] = *reinterpret_cast<const bf16x8*>(
                            Pw + (qi * 16 + lr) * 144 + (((kb << 5) + (g << 3)) << 1));
#pragma unroll
                    for (int df = 0; df < 4; ++df)
                        vf[df] = *reinterpret_cast<const bf16x8*>(
                            Vt[cur] + ((df << 4) + lr) * 144 + (((kb << 5) + (g << 3)) << 1));
#pragma unroll
                    for (int qi = 0; qi < 2; ++qi)
#pragma unroll
                        for (int df = 0; df < 4; ++df)
                            acc[qi][df] = __builtin_amdgcn_mfma_f32_16x16x32_bf16(
                                vf[df], pfv[qi], acc[qi][df], 0, 0, 0);
                }
            }

            if (pf_) {
                uint4 a, bq;
                a.x = (vreg[0] & 0xffffu) | (vreg[1] << 16);
                a.y = (vreg[2] & 0xffffu) | (vreg[3] << 16);
                a.z = (vreg[4] & 0xffffu) | (vreg[5] << 16);
                a.w = (vreg[6] & 0xffffu) | (vreg[7] << 16);
                bq.x = (vreg[0] >> 16) | (vreg[1] & 0xffff0000u);
                bq.y = (vreg[2] >> 16) | (vreg[3] & 0xffff0000u);
                bq.z = (vreg[4] >> 16) | (vreg[5] & 0xffff0000u);
                bq.w = (vreg[6] >> 16) | (vreg[7] & 0xffff0000u);
                char* vt = Vt[cur ^ 1];
                *reinterpret_cast<uint4*>(vt + vd0 * 144 + vkey0 * 2) = a;
                *reinterpret_cast<uint4*>(vt + (vd0 + 1) * 144 + vkey0 * 2) = bq;
                __syncthreads();
            }
        }

        // ---- finalize: per-lane 1/l, store O^T element-wise ----
#pragma unroll
        for (int qi = 0; qi < 2; ++qi) {
            const float li = 1.0f / lrun[qi];
            const int q = q0 + (qi << 4) + lr;
            unsigned short* op = ctx + (size_t)(b * SEQ + q) * NC + h * HD;
#pragma unroll
            for (int df = 0; df < 4; ++df)
#pragma unroll
                for (int r = 0; r < 4; ++r)
                    op[(df << 4) + (g << 2) + r] = f2bf(acc[qi][df][r] * li);
        }
    }
}

// ---------------------------------------------------------------------------
extern "C" void kernel_launch(void* const* d_in, const int* in_sizes, int n_in,
                              void* d_out, int out_size, void* d_ws, size_t ws_size,
                              hipStream_t stream) {
    const float* x     = (const float*)d_in[0];
    const float* Wqkv  = (const float*)d_in[1];
    const float* bqkv  = (const float*)d_in[2];
    const float* Wproj = (const float*)d_in[3];
    const float* bproj = (const float*)d_in[4];
    float* out = (float*)d_out;

    const int M = BATCH * SEQ;  // 8192
    unsigned short* ws = (unsigned short*)d_ws;
    unsigned short* xb     = ws;                           // 8192*1024
    unsigned short* wqkvb  = xb + (size_t)M * NC;          // 3072*1024
    unsigned short* wprojb = wqkvb + (size_t)3 * NC * NC;  // 1024*1024
    unsigned short* qkvb   = wprojb + (size_t)NC * NC;     // 8192*3072
    unsigned short* ctxb   = qkvb + (size_t)M * 3 * NC;    // 8192*1024

    {
        int n4 = M * NC / 4;
        cvt_kernel<<<(n4 + 255) / 256, 256, 0, stream>>>(x, xb, n4);
    }
    {
        int n4 = 3 * NC * NC / 4;
        cvt_kernel<<<(n4 + 255) / 256, 256, 0, stream>>>(Wqkv, wqkvb, n4);
    }
    {
        int n4 = NC * NC / 4;
        cvt_kernel<<<(n4 + 255) / 256, 256, 0, stream>>>(Wproj, wprojb, n4);
    }

    // qkv = x @ Wqkv^T + b; q-third scaled by (1/sqrt(64))*log2(e) -> exp2 softmax
    gemm_bt_kernel<true><<<(M / 128) * (3 * NC / 128), 256, 0, stream>>>(
        xb, wqkvb, bqkv, qkvb, M, 3 * NC, NC, NC, 0.18033688011112042f);

    attn_kernel<<<(SEQ / 256) * NH * BATCH, 256, 0, stream>>>(qkvb, ctxb);

    // out = ctx @ Wproj^T + b (fp32 out)
    gemm_bt_kernel<false><<<(M / 128) * (NC / 128), 256, 0, stream>>>(
        ctxb, wprojb, bproj, out, M, NC, NC, 0, 1.0f);
}

// Round 4
// 164.079 us; speedup vs baseline: 1.7119x; 1.0560x over previous
//
#include <hip/hip_runtime.h>
#include <hip/hip_bf16.h>
#include <stdint.h>

#define BATCH 4
#define SEQ   2048
#define NC    1024
#define NH    16
#define HD    64
#define NT    16   // q-tiles of 128 rows

typedef __bf16 bf16x8 __attribute__((ext_vector_type(8)));
typedef __bf16 bf16x4 __attribute__((ext_vector_type(4)));
typedef float  f32x4  __attribute__((ext_vector_type(4)));

#define DEV __device__ __forceinline__

DEV unsigned short f2bf(float f) {
    union { float f; unsigned u; } v; v.f = f;
    unsigned r = (v.u + 0x7fffu + ((v.u >> 16) & 1u)) >> 16;
    return (unsigned short)r;
}

DEV float fast_exp2(float x) {
#if __has_builtin(__builtin_amdgcn_exp2f)
    return __builtin_amdgcn_exp2f(x);
#else
    return exp2f(x);
#endif
}

// async global->LDS, 16B per lane. LDS dest must be wave-uniform base; HW adds lane*16.
#define GLDS16(gsrc, ldst)                                                           \
    __builtin_amdgcn_global_load_lds(                                                \
        (const __attribute__((address_space(1))) unsigned int*)(gsrc),               \
        (__attribute__((address_space(3))) unsigned int*)(ldst), 16, 0, 0)

// ---------------------------------------------------------------------------
// fp32 -> bf16 convert (vectorized float4 -> ushort4)
// ---------------------------------------------------------------------------
__global__ void cvt_kernel(const float* __restrict__ in, unsigned short* __restrict__ out, int n4) {
    int i = blockIdx.x * 256 + threadIdx.x;
    if (i >= n4) return;
    float4 v = reinterpret_cast<const float4*>(in)[i];
    ushort4 o;
    o.x = f2bf(v.x); o.y = f2bf(v.y); o.z = f2bf(v.z); o.w = f2bf(v.w);
    reinterpret_cast<ushort4*>(out)[i] = o;
}

// ---------------------------------------------------------------------------
// C[M,N] = A[M,K] * W[N,K]^T + bias, bf16 inputs, fp32 accum.
// 128x128 tile, BK=64, 4 waves (2x2), 16x16x32 bf16 MFMA, gload_lds staging
// with XOR chunk-swizzle. XCD-aware block swizzle (grid % 8 == 0).
// ---------------------------------------------------------------------------
template <bool BF16_OUT>
__global__ __launch_bounds__(256, 2) void gemm_bt_kernel(
    const unsigned short* __restrict__ A,
    const unsigned short* __restrict__ W,
    const float* __restrict__ bias,
    void* __restrict__ Cout,
    int M, int N, int K, int scale_n, float scale)
{
    __shared__ __align__(16) char Alds[128 * 128];
    __shared__ __align__(16) char Blds[128 * 128];

    const int tid = threadIdx.x;
    const int w = tid >> 6, l = tid & 63, g = l >> 4, lr = l & 15;
    const int nt = N >> 7;
    const int cpx = gridDim.x >> 3;
    const int bid = (blockIdx.x & 7) * cpx + (blockIdx.x >> 3);
    const int mtile = bid / nt, ntile = bid % nt;
    const int m0 = mtile << 7, n0 = ntile << 7;
    const int wr = (w >> 1) << 6, wc = (w & 1) << 6;

    f32x4 acc[4][4] = {};

    for (int kt = 0; kt < K; kt += 64) {
        if (kt) __syncthreads();
#pragma unroll
        for (int i = 0; i < 4; ++i) {
            const int issue = (i << 2) + w;
            const int row = (issue << 3) + (l >> 3);
            const int chunk = (l & 7) ^ (row & 7);
            GLDS16((const char*)(A + (size_t)(m0 + row) * K + kt) + (chunk << 4),
                   Alds + (issue << 10));
        }
#pragma unroll
        for (int i = 0; i < 4; ++i) {
            const int issue = (i << 2) + w;
            const int row = (issue << 3) + (l >> 3);
            const int chunk = (l & 7) ^ (row & 7);
            GLDS16((const char*)(W + (size_t)(n0 + row) * K + kt) + (chunk << 4),
                   Blds + (issue << 10));
        }
        __syncthreads();

#pragma unroll
        for (int kb = 0; kb < 2; ++kb) {
            bf16x8 af[4], bfr[4];
#pragma unroll
            for (int mf = 0; mf < 4; ++mf) {
                const int row = wr + (mf << 4) + lr;
                const int chunk = ((kb << 2) + g) ^ (row & 7);
                af[mf] = *reinterpret_cast<const bf16x8*>(Alds + row * 128 + (chunk << 4));
            }
#pragma unroll
            for (int nf = 0; nf < 4; ++nf) {
                const int row = wc + (nf << 4) + lr;
                const int chunk = ((kb << 2) + g) ^ (row & 7);
                bfr[nf] = *reinterpret_cast<const bf16x8*>(Blds + row * 128 + (chunk << 4));
            }
#pragma unroll
            for (int mf = 0; mf < 4; ++mf)
#pragma unroll
                for (int nf = 0; nf < 4; ++nf)
                    acc[mf][nf] = __builtin_amdgcn_mfma_f32_16x16x32_bf16(
                        af[mf], bfr[nf], acc[mf][nf], 0, 0, 0);
        }
    }

#pragma unroll
    for (int mf = 0; mf < 4; ++mf) {
#pragma unroll
        for (int nf = 0; nf < 4; ++nf) {
            const int n = n0 + wc + (nf << 4) + lr;
            const float bscale = (n < scale_n) ? scale : 1.0f;
            const float bv = bias[n];
#pragma unroll
            for (int r = 0; r < 4; ++r) {
                const int m = m0 + wr + (mf << 4) + (g << 2) + r;
                float v2 = (acc[mf][nf][r] + bv) * bscale;
                if (BF16_OUT)
                    ((unsigned short*)Cout)[(size_t)m * N + n] = f2bf(v2);
                else
                    ((float*)Cout)[(size_t)m * N + n] = v2;
            }
        }
    }
}

// ---------------------------------------------------------------------------
// Causal flash attention, heavy-first dispatch, double-buffered, O^T accum.
// Grid = 1024 blocks: one 128-row q-tile per block, qt = 15 - bid/64 so the
// in-order dispatcher runs heavy blocks first (LPT-style packing); 3 blocks/CU
// resident (LDS 52KB). Blocks sharing (h,b) are 64 apart -> same XCD under
// round-robin, preserving KV L2 reuse without an explicit swizzle.
// K dbuf via gload_lds (chunk-swizzled source); V dbuf via reg-staged
// transpose (T14). S^T = K*Q^T; PV computes O^T = V^T * P^T so corr/lrun/
// finalize are per-lane. Defer-max (THR=8, exp2 domain).
// ---------------------------------------------------------------------------
__global__ __launch_bounds__(256, 2) void attn_kernel(
    const unsigned short* __restrict__ qkv,  // [B*S, 3072] bf16
    unsigned short* __restrict__ ctx)        // [B*S, 1024] bf16
{
    __shared__ __align__(16) char Klds[2][8192];      // [64 key][64 d], chunk-swizzled
    __shared__ __align__(16) char Vt[2][64 * 144];    // [64 d][72 key pad] bf16
    __shared__ __align__(16) char Pl[4][32 * 144];    // per-wave [32 q][72 key pad] bf16

    const int tid = threadIdx.x;
    const int w = tid >> 6, l = tid & 63, g = l >> 4, lr = l & 15;
    const int bid = blockIdx.x;
    const int qt = NT - 1 - (bid >> 6);   // heavy-first
    const int h = (bid >> 2) & 15, b = bid & 3;
    const unsigned short* base = qkv + (size_t)b * SEQ * 3072 + h * 64;
    char* Pw = Pl[w];

    // V staging coords: thread loads 8 keys x 2 d (b32 each), writes 2 b128 rows
    const int vkey0 = (tid >> 5) << 3;  // 0..56 step 8
    const int vd0   = (tid & 31) << 1;  // 0..62 step 2
    const unsigned short* vbase = base + 2048 + (size_t)vkey0 * 3072 + vd0;

    const int q0 = (qt << 7) + (w << 5);
    const int ntiles = (qt + 1) << 1;

    bf16x8 qfr[2][2];
#pragma unroll
    for (int qi = 0; qi < 2; ++qi)
#pragma unroll
        for (int kb = 0; kb < 2; ++kb)
            qfr[qi][kb] = *reinterpret_cast<const bf16x8*>(
                base + (size_t)(q0 + (qi << 4) + lr) * 3072 + (kb << 5) + (g << 3));

    f32x4 acc[2][4] = {};  // acc[qi][df] = O^T: row(g*4+r)=d, col(lane&15)=q
    float mrun[2] = {-INFINITY, -INFINITY};
    float lrun[2] = {0.f, 0.f};

    uint32_t vreg[8];

    // ---- prologue: stage tile 0 ----
#pragma unroll
    for (int i = 0; i < 8; ++i)
        vreg[i] = *reinterpret_cast<const uint32_t*>(vbase + (size_t)i * 3072);
#pragma unroll
    for (int i = 0; i < 2; ++i) {
        const int issue = (i << 2) + w;
        const int row = (issue << 3) + (l >> 3);
        const int chunk = (l & 7) ^ (row & 7);
        GLDS16((const char*)(base + 1024 + (size_t)row * 3072) + (chunk << 4),
               Klds[0] + (issue << 10));
    }
    {
        uint4 a, bq;
        a.x = (vreg[0] & 0xffffu) | (vreg[1] << 16);
        a.y = (vreg[2] & 0xffffu) | (vreg[3] << 16);
        a.z = (vreg[4] & 0xffffu) | (vreg[5] << 16);
        a.w = (vreg[6] & 0xffffu) | (vreg[7] << 16);
        bq.x = (vreg[0] >> 16) | (vreg[1] & 0xffff0000u);
        bq.y = (vreg[2] >> 16) | (vreg[3] & 0xffff0000u);
        bq.z = (vreg[4] >> 16) | (vreg[5] & 0xffff0000u);
        bq.w = (vreg[6] >> 16) | (vreg[7] & 0xffff0000u);
        *reinterpret_cast<uint4*>(Vt[0] + vd0 * 144 + vkey0 * 2) = a;
        *reinterpret_cast<uint4*>(Vt[0] + (vd0 + 1) * 144 + vkey0 * 2) = bq;
    }
    __syncthreads();

    for (int t = 0; t < ntiles; ++t) {
        const int cur = t & 1;
        const int kv0 = t << 6;
        const bool pf_ = (t + 1 < ntiles);

        if (pf_) {
            const int kv1 = kv0 + 64;
#pragma unroll
            for (int i = 0; i < 8; ++i)
                vreg[i] = *reinterpret_cast<const uint32_t*>(
                    vbase + (size_t)(kv1 + i) * 3072);
#pragma unroll
            for (int i = 0; i < 2; ++i) {
                const int issue = (i << 2) + w;
                const int row = (issue << 3) + (l >> 3);
                const int chunk = (l & 7) ^ (row & 7);
                GLDS16((const char*)(base + 1024 + (size_t)(kv1 + row) * 3072) + (chunk << 4),
                       Klds[cur ^ 1] + (issue << 10));
            }
        }

        if (kv0 <= q0 + 31) {  // wave-uniform causal tile skip
            // ---- QK^T (S^T = K * Q^T): col=q, row=key ----
            f32x4 st[4][2] = {};
#pragma unroll
            for (int kb = 0; kb < 2; ++kb) {
                bf16x8 kfr[4];
#pragma unroll
                for (int kf = 0; kf < 4; ++kf) {
                    const int row = (kf << 4) + lr;
                    const int chunk = ((kb << 2) + g) ^ (row & 7);
                    kfr[kf] = *reinterpret_cast<const bf16x8*>(
                        Klds[cur] + row * 128 + (chunk << 4));
                }
#pragma unroll
                for (int kf = 0; kf < 4; ++kf)
#pragma unroll
                    for (int qi = 0; qi < 2; ++qi)
                        st[kf][qi] = __builtin_amdgcn_mfma_f32_16x16x32_bf16(
                            kfr[kf], qfr[qi][kb], st[kf][qi], 0, 0, 0);
            }
            // ---- online softmax (exp2 domain), per-lane corr ----
#pragma unroll
            for (int qi = 0; qi < 2; ++qi) {
                if (kv0 + 63 > q0 + (qi << 4)) {  // diagonal tile: mask (uniform branch)
                    const int qg = q0 + (qi << 4) + lr;
#pragma unroll
                    for (int kf = 0; kf < 4; ++kf)
#pragma unroll
                        for (int r = 0; r < 4; ++r) {
                            const int key = kv0 + (kf << 4) + (g << 2) + r;
                            if (key > qg) st[kf][qi][r] = -INFINITY;
                        }
                }
                float mt = -INFINITY;
#pragma unroll
                for (int kf = 0; kf < 4; ++kf)
#pragma unroll
                    for (int r = 0; r < 4; ++r) mt = fmaxf(mt, st[kf][qi][r]);
                mt = fmaxf(mt, __shfl_xor(mt, 16));
                mt = fmaxf(mt, __shfl_xor(mt, 32));
                if (__any(mt > mrun[qi] + 8.0f)) {  // defer-max: rescale only on growth
                    const float mnew = fmaxf(mrun[qi], mt);
                    const float corr = fast_exp2(mrun[qi] - mnew);
                    mrun[qi] = mnew;
                    lrun[qi] *= corr;
#pragma unroll
                    for (int df = 0; df < 4; ++df)
#pragma unroll
                        for (int r = 0; r < 4; ++r) acc[qi][df][r] *= corr;
                }
                float rs = 0.f;
#pragma unroll
                for (int kf = 0; kf < 4; ++kf) {
                    float p0 = fast_exp2(st[kf][qi][0] - mrun[qi]);
                    float p1 = fast_exp2(st[kf][qi][1] - mrun[qi]);
                    float p2 = fast_exp2(st[kf][qi][2] - mrun[qi]);
                    float p3 = fast_exp2(st[kf][qi][3] - mrun[qi]);
                    rs += (p0 + p1) + (p2 + p3);
                    bf16x4 pv = {(__bf16)p0, (__bf16)p1, (__bf16)p2, (__bf16)p3};
                    *reinterpret_cast<bf16x4*>(
                        Pw + (qi * 16 + lr) * 144 + (((kf << 4) + (g << 2)) << 1)) = pv;
                }
                rs += __shfl_xor(rs, 16);
                rs += __shfl_xor(rs, 32);
                lrun[qi] += rs;
            }
            // ---- PV as O^T: acc[qi][df] = V-frag(A) x P-frag(B) ----
#pragma unroll
            for (int kb = 0; kb < 2; ++kb) {
                bf16x8 pfv[2], vf[4];
#pragma unroll
                for (int qi = 0; qi < 2; ++qi)
                    pfv[qi] = *reinterpret_cast<const bf16x8*>(
                        Pw + (qi * 16 + lr) * 144 + (((kb << 5) + (g << 3)) << 1));
#pragma unroll
                for (int df = 0; df < 4; ++df)
                    vf[df] = *reinterpret_cast<const bf16x8*>(
                        Vt[cur] + ((df << 4) + lr) * 144 + (((kb << 5) + (g << 3)) << 1));
#pragma unroll
                for (int qi = 0; qi < 2; ++qi)
#pragma unroll
                    for (int df = 0; df < 4; ++df)
                        acc[qi][df] = __builtin_amdgcn_mfma_f32_16x16x32_bf16(
                            vf[df], pfv[qi], acc[qi][df], 0, 0, 0);
            }
        }

        if (pf_) {
            uint4 a, bq;
            a.x = (vreg[0] & 0xffffu) | (vreg[1] << 16);
            a.y = (vreg[2] & 0xffffu) | (vreg[3] << 16);
            a.z = (vreg[4] & 0xffffu) | (vreg[5] << 16);
            a.w = (vreg[6] & 0xffffu) | (vreg[7] << 16);
            bq.x = (vreg[0] >> 16) | (vreg[1] & 0xffff0000u);
            bq.y = (vreg[2] >> 16) | (vreg[3] & 0xffff0000u);
            bq.z = (vreg[4] >> 16) | (vreg[5] & 0xffff0000u);
            bq.w = (vreg[6] >> 16) | (vreg[7] & 0xffff0000u);
            char* vt = Vt[cur ^ 1];
            *reinterpret_cast<uint4*>(vt + vd0 * 144 + vkey0 * 2) = a;
            *reinterpret_cast<uint4*>(vt + (vd0 + 1) * 144 + vkey0 * 2) = bq;
            __syncthreads();
        }
    }

    // ---- finalize: per-lane 1/l, store O^T element-wise ----
#pragma unroll
    for (int qi = 0; qi < 2; ++qi) {
        const float li = 1.0f / lrun[qi];
        const int q = q0 + (qi << 4) + lr;
        unsigned short* op = ctx + (size_t)(b * SEQ + q) * NC + h * HD;
#pragma unroll
        for (int df = 0; df < 4; ++df)
#pragma unroll
            for (int r = 0; r < 4; ++r)
                op[(df << 4) + (g << 2) + r] = f2bf(acc[qi][df][r] * li);
    }
}

// ---------------------------------------------------------------------------
extern "C" void kernel_launch(void* const* d_in, const int* in_sizes, int n_in,
                              void* d_out, int out_size, void* d_ws, size_t ws_size,
                              hipStream_t stream) {
    const float* x     = (const float*)d_in[0];
    const float* Wqkv  = (const float*)d_in[1];
    const float* bqkv  = (const float*)d_in[2];
    const float* Wproj = (const float*)d_in[3];
    const float* bproj = (const float*)d_in[4];
    float* out = (float*)d_out;

    const int M = BATCH * SEQ;  // 8192
    unsigned short* ws = (unsigned short*)d_ws;
    unsigned short* xb     = ws;                           // 8192*1024
    unsigned short* wqkvb  = xb + (size_t)M * NC;          // 3072*1024
    unsigned short* wprojb = wqkvb + (size_t)3 * NC * NC;  // 1024*1024
    unsigned short* qkvb   = wprojb + (size_t)NC * NC;     // 8192*3072
    unsigned short* ctxb   = qkvb + (size_t)M * 3 * NC;    // 8192*1024

    {
        int n4 = M * NC / 4;
        cvt_kernel<<<(n4 + 255) / 256, 256, 0, stream>>>(x, xb, n4);
    }
    {
        int n4 = 3 * NC * NC / 4;
        cvt_kernel<<<(n4 + 255) / 256, 256, 0, stream>>>(Wqkv, wqkvb, n4);
    }
    {
        int n4 = NC * NC / 4;
        cvt_kernel<<<(n4 + 255) / 256, 256, 0, stream>>>(Wproj, wprojb, n4);
    }

    // qkv = x @ Wqkv^T + b; q-third scaled by (1/sqrt(64))*log2(e) -> exp2 softmax
    gemm_bt_kernel<true><<<(M / 128) * (3 * NC / 128), 256, 0, stream>>>(
        xb, wqkvb, bqkv, qkvb, M, 3 * NC, NC, NC, 0.18033688011112042f);

    // one q-tile per block, heavy-first (LPT) ordering; 1024 blocks
    attn_kernel<<<NT * NH * BATCH, 256, 0, stream>>>(qkvb, ctxb);

    // out = ctx @ Wproj^T + b (fp32 out)
    gemm_bt_kernel<false><<<(M / 128) * (NC / 128), 256, 0, stream>>>(
        ctxb, wprojb, bproj, out, M, NC, NC, 0, 1.0f);
}

// Round 5
// 158.786 us; speedup vs baseline: 1.7689x; 1.0333x over previous
//
#include <hip/hip_runtime.h>
#include <hip/hip_bf16.h>
#include <stdint.h>

#define BATCH 4
#define SEQ   2048
#define NC    1024
#define NH    16
#define HD    64
#define NT    16   // q-tiles of 128 rows

typedef __bf16 bf16x8 __attribute__((ext_vector_type(8)));
typedef __bf16 bf16x2 __attribute__((ext_vector_type(2)));
typedef float  f32x4  __attribute__((ext_vector_type(4)));
typedef float  f32x16 __attribute__((ext_vector_type(16)));

#define DEV __device__ __forceinline__

DEV unsigned short f2bf(float f) {
    union { float f; unsigned u; } v; v.f = f;
    unsigned r = (v.u + 0x7fffu + ((v.u >> 16) & 1u)) >> 16;
    return (unsigned short)r;
}

DEV float fast_exp2(float x) {
#if __has_builtin(__builtin_amdgcn_exp2f)
    return __builtin_amdgcn_exp2f(x);
#else
    return exp2f(x);
#endif
}

// (a', b') = swap a's hi 32 lanes with b's lo 32 lanes:
// a' = {a_lo, b_lo}, b' = {a_hi, b_hi}
DEV void plane32_swap(uint32_t& a, uint32_t& b) {
#if __has_builtin(__builtin_amdgcn_permlane32_swap)
    auto r = __builtin_amdgcn_permlane32_swap(a, b, false, false);
    a = (uint32_t)r[0];
    b = (uint32_t)r[1];
#else
    uint32_t sa = __shfl_xor(a, 32), sb = __shfl_xor(b, 32);
    const bool hi = ((threadIdx.x & 63) >= 32);
    uint32_t na = hi ? sb : a;
    uint32_t nb = hi ? b : sa;
    a = na; b = nb;
#endif
}

// async global->LDS, 16B per lane. LDS dest must be wave-uniform base; HW adds lane*16.
#define GLDS16(gsrc, ldst)                                                           \
    __builtin_amdgcn_global_load_lds(                                                \
        (const __attribute__((address_space(1))) unsigned int*)(gsrc),               \
        (__attribute__((address_space(3))) unsigned int*)(ldst), 16, 0, 0)

// ---------------------------------------------------------------------------
// fp32 -> bf16 convert (vectorized float4 -> ushort4)
// ---------------------------------------------------------------------------
__global__ void cvt_kernel(const float* __restrict__ in, unsigned short* __restrict__ out, int n4) {
    int i = blockIdx.x * 256 + threadIdx.x;
    if (i >= n4) return;
    float4 v = reinterpret_cast<const float4*>(in)[i];
    ushort4 o;
    o.x = f2bf(v.x); o.y = f2bf(v.y); o.z = f2bf(v.z); o.w = f2bf(v.w);
    reinterpret_cast<ushort4*>(out)[i] = o;
}

// ---------------------------------------------------------------------------
// C[M,N] = A[M,K] * W[N,K]^T + bias, bf16 inputs, fp32 accum. (unchanged)
// ---------------------------------------------------------------------------
template <bool BF16_OUT>
__global__ __launch_bounds__(256, 2) void gemm_bt_kernel(
    const unsigned short* __restrict__ A,
    const unsigned short* __restrict__ W,
    const float* __restrict__ bias,
    void* __restrict__ Cout,
    int M, int N, int K, int scale_n, float scale)
{
    __shared__ __align__(16) char Alds[128 * 128];
    __shared__ __align__(16) char Blds[128 * 128];

    const int tid = threadIdx.x;
    const int w = tid >> 6, l = tid & 63, g = l >> 4, lr = l & 15;
    const int nt = N >> 7;
    const int cpx = gridDim.x >> 3;
    const int bid = (blockIdx.x & 7) * cpx + (blockIdx.x >> 3);
    const int mtile = bid / nt, ntile = bid % nt;
    const int m0 = mtile << 7, n0 = ntile << 7;
    const int wr = (w >> 1) << 6, wc = (w & 1) << 6;

    f32x4 acc[4][4] = {};

    for (int kt = 0; kt < K; kt += 64) {
        if (kt) __syncthreads();
#pragma unroll
        for (int i = 0; i < 4; ++i) {
            const int issue = (i << 2) + w;
            const int row = (issue << 3) + (l >> 3);
            const int chunk = (l & 7) ^ (row & 7);
            GLDS16((const char*)(A + (size_t)(m0 + row) * K + kt) + (chunk << 4),
                   Alds + (issue << 10));
        }
#pragma unroll
        for (int i = 0; i < 4; ++i) {
            const int issue = (i << 2) + w;
            const int row = (issue << 3) + (l >> 3);
            const int chunk = (l & 7) ^ (row & 7);
            GLDS16((const char*)(W + (size_t)(n0 + row) * K + kt) + (chunk << 4),
                   Blds + (issue << 10));
        }
        __syncthreads();

#pragma unroll
        for (int kb = 0; kb < 2; ++kb) {
            bf16x8 af[4], bfr[4];
#pragma unroll
            for (int mf = 0; mf < 4; ++mf) {
                const int row = wr + (mf << 4) + lr;
                const int chunk = ((kb << 2) + g) ^ (row & 7);
                af[mf] = *reinterpret_cast<const bf16x8*>(Alds + row * 128 + (chunk << 4));
            }
#pragma unroll
            for (int nf = 0; nf < 4; ++nf) {
                const int row = wc + (nf << 4) + lr;
                const int chunk = ((kb << 2) + g) ^ (row & 7);
                bfr[nf] = *reinterpret_cast<const bf16x8*>(Blds + row * 128 + (chunk << 4));
            }
#pragma unroll
            for (int mf = 0; mf < 4; ++mf)
#pragma unroll
                for (int nf = 0; nf < 4; ++nf)
                    acc[mf][nf] = __builtin_amdgcn_mfma_f32_16x16x32_bf16(
                        af[mf], bfr[nf], acc[mf][nf], 0, 0, 0);
        }
    }

#pragma unroll
    for (int mf = 0; mf < 4; ++mf) {
#pragma unroll
        for (int nf = 0; nf < 4; ++nf) {
            const int n = n0 + wc + (nf << 4) + lr;
            const float bscale = (n < scale_n) ? scale : 1.0f;
            const float bv = bias[n];
#pragma unroll
            for (int r = 0; r < 4; ++r) {
                const int m = m0 + wr + (mf << 4) + (g << 2) + r;
                float v2 = (acc[mf][nf][r] + bv) * bscale;
                if (BF16_OUT)
                    ((unsigned short*)Cout)[(size_t)m * N + n] = f2bf(v2);
                else
                    ((float*)Cout)[(size_t)m * N + n] = v2;
            }
        }
    }
}

// ---------------------------------------------------------------------------
// Causal flash attention on 32x32x16 MFMA, heavy-first dispatch, dbuf, O^T.
// 4 waves x 32 q-rows (one q per lane column). S^T = K*Q^T (32x32): lane
// holds 32 scores for its q -> softmax = in-lane reduce + one shfl_xor(32);
// mrun/lrun per-lane scalars. P^T stays IN REGISTERS: cvt_pk pairs +
// permlane32_swap build the PV B-fragment directly (no P LDS roundtrip).
// LDS = 34.8KB -> 4 blocks/CU. K dbuf via gload_lds (chunk-swizzled source);
// V dbuf via reg-staged transpose (T14). Defer-max (THR=8, exp2 domain).
// ---------------------------------------------------------------------------
__global__ __launch_bounds__(256, 4) void attn_kernel(
    const unsigned short* __restrict__ qkv,  // [B*S, 3072] bf16
    unsigned short* __restrict__ ctx)        // [B*S, 1024] bf16
{
    __shared__ __align__(16) char Klds[2][8192];    // [64 key][64 d], chunk-swizzled
    __shared__ __align__(16) char Vt[2][64 * 144];  // [64 d][72 key pad] bf16

    const int tid = threadIdx.x;
    const int w = tid >> 6, l = tid & 63, hi = l >> 5, lq = l & 31;
    const int bid = blockIdx.x;
    const int qt = NT - 1 - (bid >> 6);   // heavy-first
    const int h = (bid >> 2) & 15, b = bid & 3;
    const unsigned short* base = qkv + (size_t)b * SEQ * 3072 + h * 64;

    // V staging coords: thread loads 8 keys x 2 d (b32 each), writes 2 b128 rows
    const int vkey0 = (tid >> 5) << 3;  // 0..56 step 8
    const int vd0   = (tid & 31) << 1;  // 0..62 step 2
    const unsigned short* vbase = base + 2048 + (size_t)vkey0 * 3072 + vd0;

    const int q0 = (qt << 7) + (w << 5);
    const int q = q0 + lq;              // this lane's q row
    const int ntiles = (qt + 1) << 1;

    // Q frags (B-operand, k=d): lane holds Q[q][ds*16 + hi*8 + j]
    bf16x8 qfr[4];
#pragma unroll
    for (int ds = 0; ds < 4; ++ds)
        qfr[ds] = *reinterpret_cast<const bf16x8*>(
            base + (size_t)q * 3072 + (ds << 4) + (hi << 3));

    f32x16 acc0 = {}, acc1 = {};  // O^T: col(lq)=q, row=d (+0 / +32)
    float mrun = -INFINITY, lrun = 0.f;

    uint32_t vreg[8];

    // ---- prologue: stage tile 0 ----
#pragma unroll
    for (int i = 0; i < 8; ++i)
        vreg[i] = *reinterpret_cast<const uint32_t*>(vbase + (size_t)i * 3072);
#pragma unroll
    for (int i = 0; i < 2; ++i) {
        const int issue = (i << 2) + w;
        const int row = (issue << 3) + (l >> 3);
        const int chunk = (l & 7) ^ (row & 7);
        GLDS16((const char*)(base + 1024 + (size_t)row * 3072) + (chunk << 4),
               Klds[0] + (issue << 10));
    }
    {
        uint4 a, bq;
        a.x = (vreg[0] & 0xffffu) | (vreg[1] << 16);
        a.y = (vreg[2] & 0xffffu) | (vreg[3] << 16);
        a.z = (vreg[4] & 0xffffu) | (vreg[5] << 16);
        a.w = (vreg[6] & 0xffffu) | (vreg[7] << 16);
        bq.x = (vreg[0] >> 16) | (vreg[1] & 0xffff0000u);
        bq.y = (vreg[2] >> 16) | (vreg[3] & 0xffff0000u);
        bq.z = (vreg[4] >> 16) | (vreg[5] & 0xffff0000u);
        bq.w = (vreg[6] >> 16) | (vreg[7] & 0xffff0000u);
        *reinterpret_cast<uint4*>(Vt[0] + vd0 * 144 + vkey0 * 2) = a;
        *reinterpret_cast<uint4*>(Vt[0] + (vd0 + 1) * 144 + vkey0 * 2) = bq;
    }
    __syncthreads();

    for (int t = 0; t < ntiles; ++t) {
        const int cur = t & 1;
        const int kv0 = t << 6;
        const bool pf_ = (t + 1 < ntiles);

        if (pf_) {
            const int kv1 = kv0 + 64;
#pragma unroll
            for (int i = 0; i < 8; ++i)
                vreg[i] = *reinterpret_cast<const uint32_t*>(
                    vbase + (size_t)(kv1 + i) * 3072);
#pragma unroll
            for (int i = 0; i < 2; ++i) {
                const int issue = (i << 2) + w;
                const int row = (issue << 3) + (l >> 3);
                const int chunk = (l & 7) ^ (row & 7);
                GLDS16((const char*)(base + 1024 + (size_t)(kv1 + row) * 3072) + (chunk << 4),
                       Klds[cur ^ 1] + (issue << 10));
            }
        }

        if (kv0 <= q0 + 31) {           // wave-uniform causal tile skip
            const bool do1 = (kv0 + 32 <= q0 + 31);  // key sub-tile 32..63 needed?

            // ---- QK^T (S^T = K * Q^T), 32x32x16: col=q, row=key ----
            f32x16 st0 = {}, st1 = {};
#pragma unroll
            for (int ds = 0; ds < 4; ++ds) {
                const int chunk = (((ds << 1) + hi) ^ (lq & 7)) << 4;
                bf16x8 k0 = *reinterpret_cast<const bf16x8*>(
                    Klds[cur] + lq * 128 + chunk);
                st0 = __builtin_amdgcn_mfma_f32_32x32x16_bf16(k0, qfr[ds], st0, 0, 0, 0);
            }
            if (do1) {
#pragma unroll
                for (int ds = 0; ds < 4; ++ds) {
                    const int chunk = (((ds << 1) + hi) ^ (lq & 7)) << 4;
                    bf16x8 k1 = *reinterpret_cast<const bf16x8*>(
                        Klds[cur] + (lq + 32) * 128 + chunk);
                    st1 = __builtin_amdgcn_mfma_f32_32x32x16_bf16(k1, qfr[ds], st1, 0, 0, 0);
                }
            }

            // ---- causal mask (key = kv0 + ktile*32 + 8*(r>>2) + (r&3) + 4*hi) ----
            if (kv0 + 31 > q0) {
#pragma unroll
                for (int r = 0; r < 16; ++r) {
                    const int key = kv0 + ((r & 3) + ((r >> 2) << 3) + (hi << 2));
                    if (key > q) st0[r] = -INFINITY;
                }
            }
            if (do1 && kv0 + 63 > q0) {
#pragma unroll
                for (int r = 0; r < 16; ++r) {
                    const int key = kv0 + 32 + ((r & 3) + ((r >> 2) << 3) + (hi << 2));
                    if (key > q) st1[r] = -INFINITY;
                }
            }

            // ---- online softmax (exp2 domain), fully per-lane ----
            float mt = st0[0];
#pragma unroll
            for (int r = 1; r < 16; ++r) mt = fmaxf(mt, st0[r]);
            if (do1) {
#pragma unroll
                for (int r = 0; r < 16; ++r) mt = fmaxf(mt, st1[r]);
            }
            mt = fmaxf(mt, __shfl_xor(mt, 32));
            if (__any(mt > mrun + 8.0f)) {  // defer-max
                const float mnew = fmaxf(mrun, mt);
                const float corr = fast_exp2(mrun - mnew);
                mrun = mnew;
                lrun *= corr;
#pragma unroll
                for (int r = 0; r < 16; ++r) { acc0[r] *= corr; acc1[r] *= corr; }
            }
            float rs = 0.f;
#pragma unroll
            for (int r = 0; r < 16; ++r) { st0[r] = fast_exp2(st0[r] - mrun); rs += st0[r]; }
            if (do1) {
#pragma unroll
                for (int r = 0; r < 16; ++r) { st1[r] = fast_exp2(st1[r] - mrun); rs += st1[r]; }
            }
            rs += __shfl_xor(rs, 32);
            lrun += rs;

            // ---- pack P to bf16 pairs: pk[s*2+c] = (P[8s+2c+4hi], P[8s+2c+1+4hi]) ----
            uint32_t pk0[8], pk1[8];
#pragma unroll
            for (int s = 0; s < 4; ++s)
#pragma unroll
                for (int c = 0; c < 2; ++c) {
                    bf16x2 t0 = {(__bf16)st0[(s << 2) + (c << 1)],
                                 (__bf16)st0[(s << 2) + (c << 1) + 1]};
                    pk0[(s << 1) + c] = __builtin_bit_cast(uint32_t, t0);
                }
            if (do1) {
#pragma unroll
                for (int s = 0; s < 4; ++s)
#pragma unroll
                    for (int c = 0; c < 2; ++c) {
                        bf16x2 t1 = {(__bf16)st1[(s << 2) + (c << 1)],
                                     (__bf16)st1[(s << 2) + (c << 1) + 1]};
                        pk1[(s << 1) + c] = __builtin_bit_cast(uint32_t, t1);
                    }
            }

            // ---- PV as O^T: per k-step, build P^T B-frag in-reg, V^T A-frag ----
            const int nkt = do1 ? 4 : 2;
#pragma unroll
            for (int kt = 0; kt < 4; ++kt) {
                if (kt >= nkt) break;
                const int s0 = (kt & 1) << 1;
                uint32_t x0, x1, y0, y1;
                if (kt < 2) {
                    x0 = pk0[(s0 << 1) + 0]; x1 = pk0[(s0 << 1) + 1];
                    y0 = pk0[(s0 << 1) + 2]; y1 = pk0[(s0 << 1) + 3];
                } else {
                    x0 = pk1[(s0 << 1) + 0]; x1 = pk1[(s0 << 1) + 1];
                    y0 = pk1[(s0 << 1) + 2]; y1 = pk1[(s0 << 1) + 3];
                }
                plane32_swap(x0, y0);  // x0 -> keys +8hi+{0,1}, y0 -> +8hi+{4,5}
                plane32_swap(x1, y1);  // x1 -> +8hi+{2,3},      y1 -> +8hi+{6,7}
                union { uint32_t u[4]; bf16x8 v; } pf;
                pf.u[0] = x0; pf.u[1] = x1; pf.u[2] = y0; pf.u[3] = y1;

                const char* vrow = Vt[cur] + ((kt << 4) + (hi << 3)) * 2;
                bf16x8 vf0 = *reinterpret_cast<const bf16x8*>(vrow + lq * 144);
                bf16x8 vf1 = *reinterpret_cast<const bf16x8*>(vrow + (lq + 32) * 144);
                acc0 = __builtin_amdgcn_mfma_f32_32x32x16_bf16(vf0, pf.v, acc0, 0, 0, 0);
                acc1 = __builtin_amdgcn_mfma_f32_32x32x16_bf16(vf1, pf.v, acc1, 0, 0, 0);
            }
        }

        if (pf_) {
            uint4 a, bq;
            a.x = (vreg[0] & 0xffffu) | (vreg[1] << 16);
            a.y = (vreg[2] & 0xffffu) | (vreg[3] << 16);
            a.z = (vreg[4] & 0xffffu) | (vreg[5] << 16);
            a.w = (vreg[6] & 0xffffu) | (vreg[7] << 16);
            bq.x = (vreg[0] >> 16) | (vreg[1] & 0xffff0000u);
            bq.y = (vreg[2] >> 16) | (vreg[3] & 0xffff0000u);
            bq.z = (vreg[4] >> 16) | (vreg[5] & 0xffff0000u);
            bq.w = (vreg[6] >> 16) | (vreg[7] & 0xffff0000u);
            char* vt = Vt[cur ^ 1];
            *reinterpret_cast<uint4*>(vt + vd0 * 144 + vkey0 * 2) = a;
            *reinterpret_cast<uint4*>(vt + (vd0 + 1) * 144 + vkey0 * 2) = bq;
            __syncthreads();
        }
    }

    // ---- finalize: per-lane 1/l, store O^T (d = (r&3)+8*(r>>2)+4*hi+32*dt) ----
    {
        const float li = 1.0f / lrun;
        unsigned short* op = ctx + (size_t)(b * SEQ + q) * NC + h * HD;
#pragma unroll
        for (int r = 0; r < 16; ++r) {
            const int d = (r & 3) + ((r >> 2) << 3) + (hi << 2);
            op[d] = f2bf(acc0[r] * li);
            op[d + 32] = f2bf(acc1[r] * li);
        }
    }
}

// ---------------------------------------------------------------------------
extern "C" void kernel_launch(void* const* d_in, const int* in_sizes, int n_in,
                              void* d_out, int out_size, void* d_ws, size_t ws_size,
                              hipStream_t stream) {
    const float* x     = (const float*)d_in[0];
    const float* Wqkv  = (const float*)d_in[1];
    const float* bqkv  = (const float*)d_in[2];
    const float* Wproj = (const float*)d_in[3];
    const float* bproj = (const float*)d_in[4];
    float* out = (float*)d_out;

    const int M = BATCH * SEQ;  // 8192
    unsigned short* ws = (unsigned short*)d_ws;
    unsigned short* xb     = ws;                           // 8192*1024
    unsigned short* wqkvb  = xb + (size_t)M * NC;          // 3072*1024
    unsigned short* wprojb = wqkvb + (size_t)3 * NC * NC;  // 1024*1024
    unsigned short* qkvb   = wprojb + (size_t)NC * NC;     // 8192*3072
    unsigned short* ctxb   = qkvb + (size_t)M * 3 * NC;    // 8192*1024

    {
        int n4 = M * NC / 4;
        cvt_kernel<<<(n4 + 255) / 256, 256, 0, stream>>>(x, xb, n4);
    }
    {
        int n4 = 3 * NC * NC / 4;
        cvt_kernel<<<(n4 + 255) / 256, 256, 0, stream>>>(Wqkv, wqkvb, n4);
    }
    {
        int n4 = NC * NC / 4;
        cvt_kernel<<<(n4 + 255) / 256, 256, 0, stream>>>(Wproj, wprojb, n4);
    }

    // qkv = x @ Wqkv^T + b; q-third scaled by (1/sqrt(64))*log2(e) -> exp2 softmax
    gemm_bt_kernel<true><<<(M / 128) * (3 * NC / 128), 256, 0, stream>>>(
        xb, wqkvb, bqkv, qkvb, M, 3 * NC, NC, NC, 0.18033688011112042f);

    // one q-tile per block, heavy-first (LPT) ordering; 1024 blocks
    attn_kernel<<<NT * NH * BATCH, 256, 0, stream>>>(qkvb, ctxb);

    // out = ctx @ Wproj^T + b (fp32 out)
    gemm_bt_kernel<false><<<(M / 128) * (NC / 128), 256, 0, stream>>>(
        ctxb, wprojb, bproj, out, M, NC, NC, 0, 1.0f);
}